// Round 14
// baseline (148.476 us; speedup 1.0000x reference)
//
#include <hip/hip_runtime.h>

using u8  = unsigned char;
using u16 = unsigned short;
using u32 = unsigned int;
typedef __attribute__((ext_vector_type(8))) short short8;   // 8 bf16 (MFMA A/B frag)
typedef __attribute__((ext_vector_type(4))) float f32x4;    // MFMA C/D frag

#define QMIN 64    // emit screen: (int)(v*32+0.5) >= 64  <=>  v >= 1.984375
#define SCAP 96    // per-row spill capacity (worst row ~58 expected spills)
#define CMAX 608   // per-row candidate max (m_all <= ~500 at +7sd)
#define RCAP 96    // ambiguous-band capacity (expected ~20, +10sd)
#define BERR 0.045f   // |v_true - v_list| bound (R10 proof implies <=0.031+2e-5)

#define AS1 __attribute__((address_space(1)))
#define AS3 __attribute__((address_space(3)))

__device__ __forceinline__ float bf2f(u16 u) {
    union { u32 i; float f; } c; c.i = ((u32)u) << 16; return c.f;
}
__device__ __forceinline__ u16 f2bf(float f) {
    union { float f; u32 i; } c; c.f = f;
    u32 u = c.i + 0x7FFFu + ((c.i >> 16) & 1u);   // RNE; inputs are finite
    return (u16)(u >> 16);
}

// entry: (n << 19) | fixed19, fixed19 = min(floor(v*65536),0x7FFFF) >= 131072
// for valid v >= 1.984 -> 0 is a safe empty sentinel. Saturated -> refine.

// ---------------------------------------------------------------------------
// Kernel 0: FRAGMENT-SWIZZLED bf16 operands + bf16 W_dec + zero spill cnt.
// Swizzle: tile t=(mt*8+kt); lane l holds 8 bf16 at (row=16*mt+(l&15),
// k=32*kt+(l>>4)*8+j) at offset (t*64+l)*8.
// ---------------------------------------------------------------------------
__global__ __launch_bounds__(256) void prep_convert(const float* __restrict__ x,
                                                    const float* __restrict__ b_dec,
                                                    const float* __restrict__ W_enc,
                                                    const float* __restrict__ W_dec,
                                                    u16* __restrict__ Ap,
                                                    u16* __restrict__ Wb,
                                                    u16* __restrict__ Wd,
                                                    u32* __restrict__ cnt) {
    int i = blockIdx.x * 256 + threadIdx.x;     // grid = 2576 blocks exactly
    if (i < 131072) {                            // A: 256 mt x 8 kt tiles
        int lane = i & 63, t = i >> 6;
        int mt = t >> 3, kt = t & 7;
        int m = mt * 16 + (lane & 15);
        int k = kt * 32 + (lane >> 4) * 8;
        const float* xs = x + (size_t)m * 256 + k;
        const float* bd = b_dec + k;
        u32 o[4];
#pragma unroll
        for (int j = 0; j < 4; j++) {
            u16 lo = f2bf(xs[2*j]   - bd[2*j]);
            u16 hi = f2bf(xs[2*j+1] - bd[2*j+1]);
            o[j] = (u32)lo | ((u32)hi << 16);
        }
        *(uint4*)(Ap + (size_t)i * 8) = make_uint4(o[0], o[1], o[2], o[3]);
    } else if (i < 393216) {                     // W_enc: 512 nt x 8 kt tiles
        int j0 = i - 131072;
        int lane = j0 & 63, t = j0 >> 6;
        int nt = t >> 3, kt = t & 7;
        int n = nt * 16 + (lane & 15);
        int k = kt * 32 + (lane >> 4) * 8;
        const float* ws = W_enc + (size_t)n * 256 + k;
        u32 o[4];
#pragma unroll
        for (int j = 0; j < 4; j++) {
            u16 lo = f2bf(ws[2*j]);
            u16 hi = f2bf(ws[2*j+1]);
            o[j] = (u32)lo | ((u32)hi << 16);
        }
        *(uint4*)(Wb + (size_t)j0 * 8) = make_uint4(o[0], o[1], o[2], o[3]);
    } else if (i < 655360) {                     // W_dec: plain bf16, 8/thread
        int j0 = i - 393216;
        const float* ws = W_dec + (size_t)j0 * 8;
        u32 o[4];
#pragma unroll
        for (int j = 0; j < 4; j++) {
            u16 lo = f2bf(ws[2*j]);
            u16 hi = f2bf(ws[2*j+1]);
            o[j] = (u32)lo | ((u32)hi << 16);
        }
        *(uint4*)(Wd + (size_t)j0 * 8) = make_uint4(o[0], o[1], o[2], o[3]);
    } else {
        int j0 = i - 655360;                     // grid end = 655360+4096
        if (j0 < 4096) cnt[j0] = 0;
    }
}

// ---------------------------------------------------------------------------
// Kernel 1: encode GEMM (4 waves x 64x64, double-buffered global_load_lds
// staging, XCD supertile swizzle). Epilogue: BALLOT-AGGREGATED cell
// insertion — one LDS atomic per 16-lane group per emit round (was up to
// 16-way serialized per-candidate atomics) — then one contiguous 4KB
// seg[x][row][8] write; overflow -> per-row spill list.
// ---------------------------------------------------------------------------
__global__ __launch_bounds__(256, 4) void encode_gemm(const u16* __restrict__ A,
                                                      const u16* __restrict__ W,
                                                      const float* __restrict__ b_enc,
                                                      u32* __restrict__ cnt,
                                                      u32* __restrict__ seg,
                                                      u32* __restrict__ spill) {
    const int tid  = threadIdx.x;
    const int lane = tid & 63;
    const int wave = tid >> 6;          // 0..3
    const int wm = wave & 1, wn = wave >> 1;

    // XCD supertile: id%8 = XCD [guide §1]; give XCD c a 16x16 block region.
    const int id = blockIdx.x + 64 * blockIdx.y;
    const int c  = id & 7, j5 = id >> 3;
    const int bx = (c & 3) * 16 + (j5 & 15);      // n-block 0..63
    const int by = (c >> 2) * 16 + (j5 >> 4);     // m-block 0..31

    const int bm0 = by * 128;           // block row base
    const int n0  = bx * 128 + wn * 64;
    const int mtb = by * 8;             // block's first m-tile
    const int ntb = bx * 8;             // block's first n-tile
    const int r15 = lane & 15;

    __shared__ u16 stg[2][16][512];     // 32 KB double-buffered staging
    __shared__ u32 cell[128][8];        // 4 KB per-row candidate cells
    __shared__ u32 l_cnt[128];

    if (tid < 128) l_cnt[tid] = 0;

    auto stage = [&](int buf, int kt) {
#pragma unroll
        for (int s2 = 0; s2 < 4; s2++) {
            int slot = wave * 4 + s2;
            const u16* g = (slot < 8)
                ? A + ((size_t)((mtb + slot) * 8 + kt) * 64 + lane) * 8
                : W + ((size_t)((ntb + (slot - 8)) * 8 + kt) * 64 + lane) * 8;
            __builtin_amdgcn_global_load_lds((const AS1 u32*)(const void*)g,
                                             (AS3 u32*)(void*)&stg[buf][slot][0],
                                             16, 0, 0);
        }
    };

    f32x4 acc[4][4] = {};
    stage(0, 0);
    __syncthreads();    // drains staging + covers l_cnt init

#pragma unroll
    for (int kt = 0; kt < 8; kt++) {
        const int cur = kt & 1, nxt = cur ^ 1;
        if (kt < 7) stage(nxt, kt + 1);     // async, in flight across MFMA
        short8 a[4], b[4];
#pragma unroll
        for (int i = 0; i < 4; i++)
            a[i] = *(const short8*)&stg[cur][wm * 4 + i][lane * 8];
#pragma unroll
        for (int j = 0; j < 4; j++)
            b[j] = *(const short8*)&stg[cur][8 + wn * 4 + j][lane * 8];
#pragma unroll
        for (int i = 0; i < 4; i++)
#pragma unroll
            for (int j = 0; j < 4; j++)
                acc[i][j] = __builtin_amdgcn_mfma_f32_16x16x32_bf16(a[i], b[j], acc[i][j], 0, 0, 0);
        __syncthreads();
    }

    // C/D layout: col(n) = lane&15, row(m) = (lane>>4)*4 + reg   [m89-verified]
    float bias[4];
#pragma unroll
    for (int j = 0; j < 4; j++) bias[j] = b_enc[n0 + j * 16 + r15];

    // --- emit: ballot-aggregated per-row cell insertion ---------------------
#pragma unroll
    for (int j = 0; j < 4; j++)
#pragma unroll
        for (int i = 0; i < 4; i++) {
            int rowl0 = wm * 64 + i * 16 + (lane >> 4) * 4;   // local row
#pragma unroll
            for (int rq = 0; rq < 4; rq++) {
                float v = acc[i][j][rq] + bias[j];
                bool cd = ((int)(v * 32.f + 0.5f) >= QMIN);
                unsigned long long mask = __ballot(cd);
                u32 gm = (u32)((mask >> ((lane >> 4) * 16)) & 0xFFFFull);
                if (gm) {                         // group-uniform
                    int rowl = rowl0 + rq;
                    int pos  = lane & 15;
                    int rank = __popc(gm & ((1u << pos) - 1u));
                    int lead = __ffs(gm) - 1;     // leader = first set lane
                    u32 base = 0;
                    if (cd && rank == 0)
                        base = atomicAdd(&l_cnt[rowl], (u32)__popc(gm));
                    base = (u32)__shfl((int)base, (lane & ~15) + lead);
                    if (cd) {
                        int n = n0 + j * 16 + r15;
                        int fx = (int)(v * 65536.f);
                        if (fx > 0x7FFFF) fx = 0x7FFFF;   // saturate -> refine
                        u32 e = ((u32)n << 19) | (u32)fx;
                        u32 off = base + (u32)rank;
                        if (off < 8) {
                            cell[rowl][off] = e;
                        } else {                  // rare spill (high-sigma rows)
                            u32 g = atomicAdd(&cnt[bm0 + rowl], 1u);
                            if (g < SCAP) spill[(size_t)(bm0 + rowl) * SCAP + g] = e;
                        }
                    }
                }
            }
        }
    __syncthreads();

    // --- one contiguous 4 KB write: seg[bx][bm0..bm0+128][8] ----------------
    {
        int row = tid >> 1, half = tid & 1;
        u32 nc = l_cnt[row];
        uint4 o;
        o.x = (half * 4 + 0 < (int)nc) ? cell[row][half * 4 + 0] : 0u;
        o.y = (half * 4 + 1 < (int)nc) ? cell[row][half * 4 + 1] : 0u;
        o.z = (half * 4 + 2 < (int)nc) ? cell[row][half * 4 + 2] : 0u;
        o.w = (half * 4 + 3 < (int)nc) ? cell[row][half * 4 + 3] : 0u;
        *(uint4*)(seg + (((size_t)bx * 4096 + bm0 + row) * 8 + half * 4)) = o;
    }
}

// ---------------------------------------------------------------------------
// Kernel 2: per row — read 64 seg cells (+spills) -> q-hist brackets T ->
// certain-in (v > Thi+2B, z = v) / ambiguous band (fp64 refine, exact
// ordering) -> decode with bf16 W_dec. Exact streaming fallback if screen
// invalid (never expected). XCD row-grouping: 512 contiguous rows per XCD.
// ---------------------------------------------------------------------------
__global__ __launch_bounds__(256) void select_decode(const u32* __restrict__ cnt,
                                                     const u32* __restrict__ seg,
                                                     const u32* __restrict__ spill,
                                                     const float* __restrict__ x,
                                                     const float* __restrict__ W_enc,
                                                     const float* __restrict__ b_enc,
                                                     const u16* __restrict__ Wd,
                                                     const float* __restrict__ b_dec,
                                                     float* __restrict__ out) {
    const int r    = (blockIdx.x & 7) * 512 + (blockIdx.x >> 3);   // XCD-grouped
    const int tid  = threadIdx.x;
    const int lane = tid & 63;
    const int wave = tid >> 6;
    const int grp  = tid >> 4;     // 16 groups of 16 lanes
    const int l16  = tid & 15;

    __shared__ float s_sae[256];
    __shared__ u32   hist[256];
    __shared__ int   wtot[4];
    __shared__ int   s_t32;
    __shared__ u32   s_m, s_c1, s_namb, s_nref;
    __shared__ int   cidx[CMAX];
    __shared__ float cval[CMAX];
    __shared__ u8    csat[CMAX];
    __shared__ short ridx[RCAP];
    __shared__ float rex[RCAP];
    __shared__ float sel_val[32];
    __shared__ int   sel_idx[32];

    s_sae[tid] = x[(size_t)r * 256 + tid] - b_dec[tid];
    hist[tid] = 0;
    if (tid == 0) { s_t32 = -1; s_m = 0; s_c1 = 0; s_namb = 0; s_nref = 0; }
    if (tid < 32) { sel_val[tid] = 0.f; sel_idx[tid] = 0; }
    __syncthreads();

    auto add_cand = [&](u32 e) {
        int fx = (int)(e & 0x7FFFFu);
        float v = (float)fx * 1.52587890625e-5f;   // /65536
        u32 p = atomicAdd(&s_m, 1u);
        if (p < CMAX) {
            cidx[p] = (int)(e >> 19);
            cval[p] = v;
            csat[p] = (fx == 0x7FFFF);
        }
        int q = (int)(v * 32.f + 0.5f); if (q > 255) q = 255;
        atomicAdd(&hist[q], 1u);
    };
    auto find_t32 = [&]() {
        int c = (int)hist[tid];
        int s = c;
#pragma unroll
        for (int off = 1; off < 64; off <<= 1) {
            int v = __shfl_down(s, off);
            if (lane + off < 64) s += v;
        }
        if (lane == 0) wtot[wave] = s;
        __syncthreads();
        int hisum = 0;
        for (int ww = wave + 1; ww < 4; ww++) hisum += wtot[ww];
        int S = s + hisum;
        if (S >= 32 && (S - c) < 32) s_t32 = tid;   // unique transition bin
        __syncthreads();
    };
    auto exact_col = [&](int col) -> double {
        const float4* wr = (const float4*)(W_enc + (size_t)col * 256 + l16 * 16);
        double s = 0.0;
#pragma unroll
        for (int u = 0; u < 4; u++) {
            float4 wv = wr[u];
            const float* sp = &s_sae[l16 * 16 + u * 4];
            s += (double)wv.x * (double)sp[0] + (double)wv.y * (double)sp[1]
               + (double)wv.z * (double)sp[2] + (double)wv.w * (double)sp[3];
        }
#pragma unroll
        for (int off = 8; off; off >>= 1) s += __shfl_down(s, off, 16);
        return s;
    };

    // --- gather candidates: 64 cells of 8 slots (thread -> (x, slot-pair)) ---
    {
        int xb = tid >> 2, sp = (tid & 3) * 2;
        const u32* cp = seg + ((size_t)xb * 4096 + r) * 8 + sp;
        u32 e0 = cp[0], e1 = cp[1];
        if (e0) add_cand(e0);
        if (e1) add_cand(e1);
    }
    const int nsp_all = (int)cnt[r];
    const int nsp = nsp_all < SCAP ? nsp_all : SCAP;
    for (int i = tid; i < nsp; i += 256)
        add_cand(spill[(size_t)r * SCAP + i]);
    __syncthreads();
    const int m = (int)s_m < CMAX ? (int)s_m : CMAX;
    find_t32();

    // t32 >= 67 <=> Tlo-2B >= 1.984 (emit screen) -> non-listed certainly out
    const bool fb_pre = (nsp_all > SCAP) || ((int)s_m > CMAX) || (s_t32 < 67);

    if (!fb_pre) {
        const float Thi = (s_t32 + 0.5f) * 0.03125f;
        const float Tlo = (s_t32 - 0.5f) * 0.03125f;
        for (int i = tid; i < m; i += 256) {
            float v = cval[i];
            if (!csat[i] && v > Thi + 2.f * BERR) {   // certainly in true top-32
                u32 p = atomicAdd(&s_c1, 1u);
                if (p < 32) { sel_val[p] = v; sel_idx[p] = cidx[i]; }
            } else if (csat[i] || v >= Tlo - 2.f * BERR) {  // ambiguous band
                u32 p = atomicAdd(&s_namb, 1u);
                if (p < RCAP) ridx[p] = (short)i;
            }
        }
    }
    __syncthreads();
    const int c1 = (int)s_c1, namb = (int)s_namb;
    const bool fb = fb_pre || (namb > RCAP) || (c1 > 31);

    if (!fb) {
        // --- fp64 refine of ambiguous band: 2 per 16-lane group per pass ----
        for (int t0 = 0; t0 < namb; t0 += 32) {
            int cA = t0 + grp, cB = t0 + grp + 16;
            if (cA < namb) {
                int iA = cidx[ridx[cA]];
                double s = exact_col(iA);
                if (l16 == 0) {
                    float f = (float)(s + (double)b_enc[iA]);
                    rex[cA] = f > 0.f ? f : 0.f;
                }
            }
            if (cB < namb) {
                int iB = cidx[ridx[cB]];
                double s = exact_col(iB);
                if (l16 == 0) {
                    float f = (float)(s + (double)b_enc[iB]);
                    rex[cB] = f > 0.f ? f : 0.f;
                }
            }
        }
        __syncthreads();

        // --- top (32-c1) of band by (exact desc, idx asc) --------------------
        const int need = 32 - c1;
        for (int k = tid; k < namb; k += 256) {
            float vi = rex[k];
            int   ii = cidx[ridx[k]];
            int rank = 0;
            for (int j = 0; j < namb; j++) {
                float vj = rex[j];
                rank += (vj > vi) || (vj == vi && cidx[ridx[j]] < ii);
            }
            if (rank < need) { sel_val[c1 + rank] = vi; sel_idx[c1 + rank] = ii; }
        }
        __syncthreads();
    } else {
        // --- exact streaming fallback over all 8192 cols (never expected) ---
        hist[tid] = 0;
        if (tid == 0) { s_t32 = -1; s_nref = 0; }
        __syncthreads();
        for (int it = 0; it < 512; it++) {
            int col = it * 16 + grp;
            double s = exact_col(col);
            if (l16 == 0) {
                float f = (float)(s + (double)b_enc[col]);
                f = f > 0.f ? f : 0.f;
                int q = (int)(f * 32.f + 0.5f); if (q > 255) q = 255;
                if (q >= 1) atomicAdd(&hist[q], 1u);
            }
        }
        __syncthreads();
        find_t32();
        int qlo = s_t32 >= 3 ? s_t32 - 2 : 1;
        for (int pass = 0; pass < 2; pass++) {
            for (int it = 0; it < 512; it++) {
                int col = it * 16 + grp;
                double s = exact_col(col);
                if (l16 == 0) {
                    float f = (float)(s + (double)b_enc[col]);
                    f = f > 0.f ? f : 0.f;
                    int q = (int)(f * 32.f + 0.5f); if (q > 255) q = 255;
                    if (q >= qlo) {
                        u32 p = atomicAdd(&s_nref, 1u);
                        if (p < CMAX) { cidx[p] = col; cval[p] = f; }
                    }
                }
            }
            __syncthreads();
            if ((int)s_nref <= CMAX) break;
            if (tid == 0) s_nref = 0;
            qlo = s_t32 > 0 ? s_t32 : 1;
            __syncthreads();
        }
        int nf = (int)s_nref; if (nf > CMAX) nf = CMAX;
        for (int k = tid; k < nf; k += 256) {
            float vi = cval[k]; int ii = cidx[k]; int rank = 0;
            for (int j = 0; j < nf; j++)
                rank += (cval[j] > vi) || (cval[j] == vi && cidx[j] < ii);
            if (rank < 32) { sel_val[rank] = vi; sel_idx[rank] = ii; }
        }
        __syncthreads();
    }

    // --- decode: out[r] = b_dec + sum_k z_k * bf16(W_dec)[idx_k] ------------
    u16 wv[32];
#pragma unroll
    for (int k = 0; k < 32; k++)
        wv[k] = Wd[(size_t)sel_idx[k] * 256 + tid];   // 32 independent loads
    float acc = b_dec[tid];
#pragma unroll
    for (int k = 0; k < 32; k++)
        acc += sel_val[k] * bf2f(wv[k]);
    out[(size_t)r * 256 + tid] = acc;
}

// ---------------------------------------------------------------------------
// ws layout (19.5 MB; ws_size is 256 MB per the poison-fill counters):
//   cnt 16 KB | seg 8 MB | spill 1.5 MB | Ap 2 MB | Wb 4 MB | Wd 4 MB
// ---------------------------------------------------------------------------
extern "C" void kernel_launch(void* const* d_in, const int* in_sizes, int n_in,
                              void* d_out, int out_size, void* d_ws, size_t ws_size,
                              hipStream_t stream) {
    const float* x     = (const float*)d_in[0];   // [4096,256] f32
    const float* W_enc = (const float*)d_in[1];   // [8192,256] f32
    const float* b_enc = (const float*)d_in[2];   // [8192]     f32
    const float* W_dec = (const float*)d_in[3];   // [8192,256] f32
    const float* b_dec = (const float*)d_in[4];   // [256]      f32
    float* out = (float*)d_out;                   // [4096,256] f32

    u32* cnt   = (u32*)d_ws;                            // 16 KB spill counters
    u32* seg   = cnt + 4096;                            // 8 MB fixed cells
    u32* spill = seg + (size_t)64 * 4096 * 8;           // 1.5 MB spill lists
    u16* Ap    = (u16*)(spill + (size_t)4096 * SCAP);   // 2 MB swizzled bf16(x-b_dec)
    u16* Wb    = Ap + (size_t)4096 * 256;               // 4 MB swizzled bf16(W_enc)
    u16* Wd    = Wb + (size_t)8192 * 256;               // 4 MB bf16(W_dec)

    prep_convert<<<2576, 256, 0, stream>>>(x, b_dec, W_enc, W_dec, Ap, Wb, Wd, cnt);
    encode_gemm<<<dim3(64, 32), 256, 0, stream>>>(Ap, Wb, b_enc, cnt, seg, spill);
    select_decode<<<4096, 256, 0, stream>>>(cnt, seg, spill, x, W_enc, b_enc, Wd, b_dec, out);
}

// Round 15
// 139.642 us; speedup vs baseline: 1.0633x; 1.0633x over previous
//
#include <hip/hip_runtime.h>

using u8  = unsigned char;
using u16 = unsigned short;
using u32 = unsigned int;
typedef __attribute__((ext_vector_type(8))) short short8;   // 8 bf16 (MFMA A/B frag)
typedef __attribute__((ext_vector_type(4))) float f32x4;    // MFMA C/D frag

#define QMIN 64    // emit screen: (int)(v*32+0.5) >= 64  <=>  v >= 1.984375
#define SCAP 96    // per-row spill capacity (worst row ~58 expected spills)
#define CMAX 608   // per-row candidate max (m_all <= ~500 at +7sd)
#define RCAP 96    // ambiguous-band capacity (expected ~20, +10sd)
#define BERR 0.045f   // |v_true - v_list| bound (R10 proof implies <=0.031+2e-5)

#define AS1 __attribute__((address_space(1)))
#define AS3 __attribute__((address_space(3)))

__device__ __forceinline__ float bf2f(u16 u) {
    union { u32 i; float f; } c; c.i = ((u32)u) << 16; return c.f;
}
__device__ __forceinline__ u16 f2bf(float f) {
    union { float f; u32 i; } c; c.f = f;
    u32 u = c.i + 0x7FFFu + ((c.i >> 16) & 1u);   // RNE; inputs are finite
    return (u16)(u >> 16);
}

// entry: (n << 19) | fixed19, fixed19 = min(floor(v*65536),0x7FFFF) >= 131072
// for valid v >= 1.984 -> 0 is a safe empty sentinel. Saturated -> refine.

// ---------------------------------------------------------------------------
// Kernel 0: FRAGMENT-SWIZZLED bf16 operands + bf16 W_dec + zero spill cnt.
// Swizzle: tile t=(mt*8+kt); lane l holds 8 bf16 at (row=16*mt+(l&15),
// k=32*kt+(l>>4)*8+j) at offset (t*64+l)*8.
// ---------------------------------------------------------------------------
__global__ __launch_bounds__(256) void prep_convert(const float* __restrict__ x,
                                                    const float* __restrict__ b_dec,
                                                    const float* __restrict__ W_enc,
                                                    const float* __restrict__ W_dec,
                                                    u16* __restrict__ Ap,
                                                    u16* __restrict__ Wb,
                                                    u16* __restrict__ Wd,
                                                    u32* __restrict__ cnt) {
    int i = blockIdx.x * 256 + threadIdx.x;     // grid = 2576 blocks exactly
    if (i < 131072) {                            // A: 256 mt x 8 kt tiles
        int lane = i & 63, t = i >> 6;
        int mt = t >> 3, kt = t & 7;
        int m = mt * 16 + (lane & 15);
        int k = kt * 32 + (lane >> 4) * 8;
        const float* xs = x + (size_t)m * 256 + k;
        const float* bd = b_dec + k;
        u32 o[4];
#pragma unroll
        for (int j = 0; j < 4; j++) {
            u16 lo = f2bf(xs[2*j]   - bd[2*j]);
            u16 hi = f2bf(xs[2*j+1] - bd[2*j+1]);
            o[j] = (u32)lo | ((u32)hi << 16);
        }
        *(uint4*)(Ap + (size_t)i * 8) = make_uint4(o[0], o[1], o[2], o[3]);
    } else if (i < 393216) {                     // W_enc: 512 nt x 8 kt tiles
        int j0 = i - 131072;
        int lane = j0 & 63, t = j0 >> 6;
        int nt = t >> 3, kt = t & 7;
        int n = nt * 16 + (lane & 15);
        int k = kt * 32 + (lane >> 4) * 8;
        const float* ws = W_enc + (size_t)n * 256 + k;
        u32 o[4];
#pragma unroll
        for (int j = 0; j < 4; j++) {
            u16 lo = f2bf(ws[2*j]);
            u16 hi = f2bf(ws[2*j+1]);
            o[j] = (u32)lo | ((u32)hi << 16);
        }
        *(uint4*)(Wb + (size_t)j0 * 8) = make_uint4(o[0], o[1], o[2], o[3]);
    } else if (i < 655360) {                     // W_dec: plain bf16, 8/thread
        int j0 = i - 393216;
        const float* ws = W_dec + (size_t)j0 * 8;
        u32 o[4];
#pragma unroll
        for (int j = 0; j < 4; j++) {
            u16 lo = f2bf(ws[2*j]);
            u16 hi = f2bf(ws[2*j+1]);
            o[j] = (u32)lo | ((u32)hi << 16);
        }
        *(uint4*)(Wd + (size_t)j0 * 8) = make_uint4(o[0], o[1], o[2], o[3]);
    } else {
        int j0 = i - 655360;                     // grid end = 655360+4096
        if (j0 < 4096) cnt[j0] = 0;
    }
}

// ---------------------------------------------------------------------------
// Kernel 1: encode GEMM (4 waves x 64x64, double-buffered global_load_lds
// staging). XCD supertile swizzle (16x16 region per XCD -> 2MB/XCD L2
// footprint). Epilogue: candidates into per-row LDS cells (<=8), then ONE
// contiguous 4KB write to seg[x][row][8]; overflow -> per-row spill list.
// [R14 lesson: ballot-aggregated insertion regressed — per-round fixed cost
// exceeded the removed atomic contention. Keep simple atomics.]
// ---------------------------------------------------------------------------
__global__ __launch_bounds__(256, 4) void encode_gemm(const u16* __restrict__ A,
                                                      const u16* __restrict__ W,
                                                      const float* __restrict__ b_enc,
                                                      u32* __restrict__ cnt,
                                                      u32* __restrict__ seg,
                                                      u32* __restrict__ spill) {
    const int tid  = threadIdx.x;
    const int lane = tid & 63;
    const int wave = tid >> 6;          // 0..3
    const int wm = wave & 1, wn = wave >> 1;

    // XCD supertile: id%8 = XCD [guide §1]; give XCD c a 16x16 block region.
    const int id = blockIdx.x + 64 * blockIdx.y;
    const int c  = id & 7, j5 = id >> 3;
    const int bx = (c & 3) * 16 + (j5 & 15);      // n-block 0..63
    const int by = (c >> 2) * 16 + (j5 >> 4);     // m-block 0..31

    const int bm0 = by * 128;           // block row base
    const int n0  = bx * 128 + wn * 64;
    const int mtb = by * 8;             // block's first m-tile
    const int ntb = bx * 8;             // block's first n-tile
    const int r15 = lane & 15;

    __shared__ u16 stg[2][16][512];     // 32 KB double-buffered staging
    __shared__ u32 cell[128][8];        // 4 KB per-row candidate cells
    __shared__ u32 l_cnt[128];

    if (tid < 128) l_cnt[tid] = 0;

    auto stage = [&](int buf, int kt) {
#pragma unroll
        for (int s2 = 0; s2 < 4; s2++) {
            int slot = wave * 4 + s2;
            const u16* g = (slot < 8)
                ? A + ((size_t)((mtb + slot) * 8 + kt) * 64 + lane) * 8
                : W + ((size_t)((ntb + (slot - 8)) * 8 + kt) * 64 + lane) * 8;
            __builtin_amdgcn_global_load_lds((const AS1 u32*)(const void*)g,
                                             (AS3 u32*)(void*)&stg[buf][slot][0],
                                             16, 0, 0);
        }
    };

    f32x4 acc[4][4] = {};
    stage(0, 0);
    __syncthreads();    // drains staging + covers l_cnt init

#pragma unroll
    for (int kt = 0; kt < 8; kt++) {
        const int cur = kt & 1, nxt = cur ^ 1;
        if (kt < 7) stage(nxt, kt + 1);     // async, in flight across MFMA
        short8 a[4], b[4];
#pragma unroll
        for (int i = 0; i < 4; i++)
            a[i] = *(const short8*)&stg[cur][wm * 4 + i][lane * 8];
#pragma unroll
        for (int j = 0; j < 4; j++)
            b[j] = *(const short8*)&stg[cur][8 + wn * 4 + j][lane * 8];
#pragma unroll
        for (int i = 0; i < 4; i++)
#pragma unroll
            for (int j = 0; j < 4; j++)
                acc[i][j] = __builtin_amdgcn_mfma_f32_16x16x32_bf16(a[i], b[j], acc[i][j], 0, 0, 0);
        __syncthreads();
    }

    // C/D layout: col(n) = lane&15, row(m) = (lane>>4)*4 + reg   [m89-verified]
    float bias[4];
#pragma unroll
    for (int j = 0; j < 4; j++) bias[j] = b_enc[n0 + j * 16 + r15];

    // --- emit candidates into per-row LDS cells -----------------------------
#pragma unroll
    for (int j = 0; j < 4; j++)
#pragma unroll
        for (int i = 0; i < 4; i++) {
            int rowl0 = wm * 64 + i * 16 + (lane >> 4) * 4;   // local row
#pragma unroll
            for (int rq = 0; rq < 4; rq++) {
                float v = acc[i][j][rq] + bias[j];
                if ((int)(v * 32.f + 0.5f) >= QMIN) {
                    int rowl = rowl0 + rq;
                    int n = n0 + j * 16 + r15;
                    int fx = (int)(v * 65536.f);
                    if (fx > 0x7FFFF) fx = 0x7FFFF;   // saturate -> forced refine
                    u32 e = ((u32)n << 19) | (u32)fx;
                    u32 off = atomicAdd(&l_cnt[rowl], 1u);
                    if (off < 8) {
                        cell[rowl][off] = e;
                    } else {                           // rare spill (high-sigma rows)
                        u32 g = atomicAdd(&cnt[bm0 + rowl], 1u);
                        if (g < SCAP) spill[(size_t)(bm0 + rowl) * SCAP + g] = e;
                    }
                }
            }
        }
    __syncthreads();

    // --- one contiguous 4 KB write: seg[bx][bm0..bm0+128][8] ----------------
    {
        int row = tid >> 1, half = tid & 1;
        u32 nc = l_cnt[row];
        uint4 o;
        o.x = (half * 4 + 0 < (int)nc) ? cell[row][half * 4 + 0] : 0u;
        o.y = (half * 4 + 1 < (int)nc) ? cell[row][half * 4 + 1] : 0u;
        o.z = (half * 4 + 2 < (int)nc) ? cell[row][half * 4 + 2] : 0u;
        o.w = (half * 4 + 3 < (int)nc) ? cell[row][half * 4 + 3] : 0u;
        *(uint4*)(seg + (((size_t)bx * 4096 + bm0 + row) * 8 + half * 4)) = o;
    }
}

// ---------------------------------------------------------------------------
// Kernel 2: per row — read 64 seg cells (+spills) -> q-hist brackets T ->
// certain-in (v > Thi+2B, z = v) / ambiguous band (fp64 refine, exact
// ordering) -> decode with bf16 W_dec. Exact streaming fallback if screen
// invalid (never expected). XCD row-grouping: 512 contiguous rows per XCD.
// ---------------------------------------------------------------------------
__global__ __launch_bounds__(256) void select_decode(const u32* __restrict__ cnt,
                                                     const u32* __restrict__ seg,
                                                     const u32* __restrict__ spill,
                                                     const float* __restrict__ x,
                                                     const float* __restrict__ W_enc,
                                                     const float* __restrict__ b_enc,
                                                     const u16* __restrict__ Wd,
                                                     const float* __restrict__ b_dec,
                                                     float* __restrict__ out) {
    const int r    = (blockIdx.x & 7) * 512 + (blockIdx.x >> 3);   // XCD-grouped
    const int tid  = threadIdx.x;
    const int lane = tid & 63;
    const int wave = tid >> 6;
    const int grp  = tid >> 4;     // 16 groups of 16 lanes
    const int l16  = tid & 15;

    __shared__ float s_sae[256];
    __shared__ u32   hist[256];
    __shared__ int   wtot[4];
    __shared__ int   s_t32;
    __shared__ u32   s_m, s_c1, s_namb, s_nref;
    __shared__ int   cidx[CMAX];
    __shared__ float cval[CMAX];
    __shared__ u8    csat[CMAX];
    __shared__ short ridx[RCAP];
    __shared__ float rex[RCAP];
    __shared__ float sel_val[32];
    __shared__ int   sel_idx[32];

    s_sae[tid] = x[(size_t)r * 256 + tid] - b_dec[tid];
    hist[tid] = 0;
    if (tid == 0) { s_t32 = -1; s_m = 0; s_c1 = 0; s_namb = 0; s_nref = 0; }
    if (tid < 32) { sel_val[tid] = 0.f; sel_idx[tid] = 0; }
    __syncthreads();

    auto add_cand = [&](u32 e) {
        int fx = (int)(e & 0x7FFFFu);
        float v = (float)fx * 1.52587890625e-5f;   // /65536
        u32 p = atomicAdd(&s_m, 1u);
        if (p < CMAX) {
            cidx[p] = (int)(e >> 19);
            cval[p] = v;
            csat[p] = (fx == 0x7FFFF);
        }
        int q = (int)(v * 32.f + 0.5f); if (q > 255) q = 255;
        atomicAdd(&hist[q], 1u);
    };
    auto find_t32 = [&]() {
        int c = (int)hist[tid];
        int s = c;
#pragma unroll
        for (int off = 1; off < 64; off <<= 1) {
            int v = __shfl_down(s, off);
            if (lane + off < 64) s += v;
        }
        if (lane == 0) wtot[wave] = s;
        __syncthreads();
        int hisum = 0;
        for (int ww = wave + 1; ww < 4; ww++) hisum += wtot[ww];
        int S = s + hisum;
        if (S >= 32 && (S - c) < 32) s_t32 = tid;   // unique transition bin
        __syncthreads();
    };
    auto exact_col = [&](int col) -> double {
        const float4* wr = (const float4*)(W_enc + (size_t)col * 256 + l16 * 16);
        double s = 0.0;
#pragma unroll
        for (int u = 0; u < 4; u++) {
            float4 wv = wr[u];
            const float* sp = &s_sae[l16 * 16 + u * 4];
            s += (double)wv.x * (double)sp[0] + (double)wv.y * (double)sp[1]
               + (double)wv.z * (double)sp[2] + (double)wv.w * (double)sp[3];
        }
#pragma unroll
        for (int off = 8; off; off >>= 1) s += __shfl_down(s, off, 16);
        return s;
    };

    // --- gather candidates: 64 cells of 8 slots (thread -> (x, slot-pair)) ---
    {
        int xb = tid >> 2, sp = (tid & 3) * 2;
        const u32* cp = seg + ((size_t)xb * 4096 + r) * 8 + sp;
        u32 e0 = cp[0], e1 = cp[1];
        if (e0) add_cand(e0);
        if (e1) add_cand(e1);
    }
    const int nsp_all = (int)cnt[r];
    const int nsp = nsp_all < SCAP ? nsp_all : SCAP;
    for (int i = tid; i < nsp; i += 256)
        add_cand(spill[(size_t)r * SCAP + i]);
    __syncthreads();
    const int m = (int)s_m < CMAX ? (int)s_m : CMAX;
    find_t32();

    // t32 >= 67 <=> Tlo-2B >= 1.984 (emit screen) -> non-listed certainly out
    const bool fb_pre = (nsp_all > SCAP) || ((int)s_m > CMAX) || (s_t32 < 67);

    if (!fb_pre) {
        const float Thi = (s_t32 + 0.5f) * 0.03125f;
        const float Tlo = (s_t32 - 0.5f) * 0.03125f;
        for (int i = tid; i < m; i += 256) {
            float v = cval[i];
            if (!csat[i] && v > Thi + 2.f * BERR) {   // certainly in true top-32
                u32 p = atomicAdd(&s_c1, 1u);
                if (p < 32) { sel_val[p] = v; sel_idx[p] = cidx[i]; }
            } else if (csat[i] || v >= Tlo - 2.f * BERR) {  // ambiguous band
                u32 p = atomicAdd(&s_namb, 1u);
                if (p < RCAP) ridx[p] = (short)i;
            }
        }
    }
    __syncthreads();
    const int c1 = (int)s_c1, namb = (int)s_namb;
    const bool fb = fb_pre || (namb > RCAP) || (c1 > 31);

    if (!fb) {
        // --- fp64 refine of ambiguous band: 2 per 16-lane group per pass ----
        for (int t0 = 0; t0 < namb; t0 += 32) {
            int cA = t0 + grp, cB = t0 + grp + 16;
            if (cA < namb) {
                int iA = cidx[ridx[cA]];
                double s = exact_col(iA);
                if (l16 == 0) {
                    float f = (float)(s + (double)b_enc[iA]);
                    rex[cA] = f > 0.f ? f : 0.f;
                }
            }
            if (cB < namb) {
                int iB = cidx[ridx[cB]];
                double s = exact_col(iB);
                if (l16 == 0) {
                    float f = (float)(s + (double)b_enc[iB]);
                    rex[cB] = f > 0.f ? f : 0.f;
                }
            }
        }
        __syncthreads();

        // --- top (32-c1) of band by (exact desc, idx asc) --------------------
        const int need = 32 - c1;
        for (int k = tid; k < namb; k += 256) {
            float vi = rex[k];
            int   ii = cidx[ridx[k]];
            int rank = 0;
            for (int j = 0; j < namb; j++) {
                float vj = rex[j];
                rank += (vj > vi) || (vj == vi && cidx[ridx[j]] < ii);
            }
            if (rank < need) { sel_val[c1 + rank] = vi; sel_idx[c1 + rank] = ii; }
        }
        __syncthreads();
    } else {
        // --- exact streaming fallback over all 8192 cols (never expected) ---
        hist[tid] = 0;
        if (tid == 0) { s_t32 = -1; s_nref = 0; }
        __syncthreads();
        for (int it = 0; it < 512; it++) {
            int col = it * 16 + grp;
            double s = exact_col(col);
            if (l16 == 0) {
                float f = (float)(s + (double)b_enc[col]);
                f = f > 0.f ? f : 0.f;
                int q = (int)(f * 32.f + 0.5f); if (q > 255) q = 255;
                if (q >= 1) atomicAdd(&hist[q], 1u);
            }
        }
        __syncthreads();
        find_t32();
        int qlo = s_t32 >= 3 ? s_t32 - 2 : 1;
        for (int pass = 0; pass < 2; pass++) {
            for (int it = 0; it < 512; it++) {
                int col = it * 16 + grp;
                double s = exact_col(col);
                if (l16 == 0) {
                    float f = (float)(s + (double)b_enc[col]);
                    f = f > 0.f ? f : 0.f;
                    int q = (int)(f * 32.f + 0.5f); if (q > 255) q = 255;
                    if (q >= qlo) {
                        u32 p = atomicAdd(&s_nref, 1u);
                        if (p < CMAX) { cidx[p] = col; cval[p] = f; }
                    }
                }
            }
            __syncthreads();
            if ((int)s_nref <= CMAX) break;
            if (tid == 0) s_nref = 0;
            qlo = s_t32 > 0 ? s_t32 : 1;
            __syncthreads();
        }
        int nf = (int)s_nref; if (nf > CMAX) nf = CMAX;
        for (int k = tid; k < nf; k += 256) {
            float vi = cval[k]; int ii = cidx[k]; int rank = 0;
            for (int j = 0; j < nf; j++)
                rank += (cval[j] > vi) || (cval[j] == vi && cidx[j] < ii);
            if (rank < 32) { sel_val[rank] = vi; sel_idx[rank] = ii; }
        }
        __syncthreads();
    }

    // --- decode: out[r] = b_dec + sum_k z_k * bf16(W_dec)[idx_k] ------------
    u16 wv[32];
#pragma unroll
    for (int k = 0; k < 32; k++)
        wv[k] = Wd[(size_t)sel_idx[k] * 256 + tid];   // 32 independent loads
    float acc = b_dec[tid];
#pragma unroll
    for (int k = 0; k < 32; k++)
        acc += sel_val[k] * bf2f(wv[k]);
    out[(size_t)r * 256 + tid] = acc;
}

// ---------------------------------------------------------------------------
// ws layout (19.5 MB; ws_size is 256 MB per the poison-fill counters):
//   cnt 16 KB | seg 8 MB | spill 1.5 MB | Ap 2 MB | Wb 4 MB | Wd 4 MB
// ---------------------------------------------------------------------------
extern "C" void kernel_launch(void* const* d_in, const int* in_sizes, int n_in,
                              void* d_out, int out_size, void* d_ws, size_t ws_size,
                              hipStream_t stream) {
    const float* x     = (const float*)d_in[0];   // [4096,256] f32
    const float* W_enc = (const float*)d_in[1];   // [8192,256] f32
    const float* b_enc = (const float*)d_in[2];   // [8192]     f32
    const float* W_dec = (const float*)d_in[3];   // [8192,256] f32
    const float* b_dec = (const float*)d_in[4];   // [256]      f32
    float* out = (float*)d_out;                   // [4096,256] f32

    u32* cnt   = (u32*)d_ws;                            // 16 KB spill counters
    u32* seg   = cnt + 4096;                            // 8 MB fixed cells
    u32* spill = seg + (size_t)64 * 4096 * 8;           // 1.5 MB spill lists
    u16* Ap    = (u16*)(spill + (size_t)4096 * SCAP);   // 2 MB swizzled bf16(x-b_dec)
    u16* Wb    = Ap + (size_t)4096 * 256;               // 4 MB swizzled bf16(W_enc)
    u16* Wd    = Wb + (size_t)8192 * 256;               // 4 MB bf16(W_dec)

    prep_convert<<<2576, 256, 0, stream>>>(x, b_dec, W_enc, W_dec, Ap, Wb, Wd, cnt);
    encode_gemm<<<dim3(64, 32), 256, 0, stream>>>(Ap, Wb, b_enc, cnt, seg, spill);
    select_decode<<<4096, 256, 0, stream>>>(cnt, seg, spill, x, W_enc, b_enc, Wd, b_dec, out);
}